// Round 1
// baseline (1379.891 us; speedup 1.0000x reference)
//
#include <hip/hip_runtime.h>
#include <hip/hip_bf16.h>
#include <math.h>

// Model dims (fixed by reference)
#define BB 4
#define NN 128
#define HH 512
#define NHEAD 8
#define HD 64
#define TN 512
#define MH 2048
// SCALE = HD^-0.5 = 0.125

__device__ __forceinline__ float gelu_f(float x) {
    float x3 = x * x * x;
    return 0.5f * x * (1.0f + tanhf(0.7978845608028654f * (x + 0.044715f * x3)));
}

// ---------------- tsym = topo + topo^T ----------------
__global__ __launch_bounds__(256) void tsym_k(const float* __restrict__ topo,
                                              float* __restrict__ tsym) {
    int idx = blockIdx.x * 256 + threadIdx.x;          // B*N*N = 65536
    int b = idx >> 14, i = (idx >> 7) & 127, j = idx & 127;
    tsym[idx] = topo[idx] + topo[(b << 14) + (j << 7) + i];
}

// ---------------- x0 = tsym@w_topo + b_topo + weight*w_w + b_w + n_emb ----------------
__global__ __launch_bounds__(256) void x0_k(const float* __restrict__ tsym,
                                            const float* __restrict__ w_topo,
                                            const float* __restrict__ b_topo,
                                            const float* __restrict__ weight,
                                            const float* __restrict__ w_w,
                                            const float* __restrict__ b_w,
                                            const float* __restrict__ n_emb,
                                            float* __restrict__ x) {
    int idx = blockIdx.x * 256 + threadIdx.x;          // TN*H = 262144
    int hcol = idx & 511;
    int bn = idx >> 9;
    int n = bn & 127;
    const float* trow = tsym + bn * 128;
    float acc = 0.0f;
#pragma unroll 8
    for (int m = 0; m < 128; ++m) acc += trow[m] * w_topo[m * 512 + hcol];
    acc += b_topo[hcol] + weight[bn] * w_w[hcol] + b_w[hcol] + n_emb[n * 512 + hcol];
    x[idx] = acc;
}

// ---------------- LayerNorm (no affine), row length 512 ----------------
__global__ __launch_bounds__(256) void ln_k(const float* __restrict__ x,
                                            float* __restrict__ h) {
    int row = blockIdx.x;
    int tid = threadIdx.x;
    const float* xr = x + row * 512;
    float v0 = xr[tid], v1 = xr[tid + 256];
    __shared__ float red[256];
    red[tid] = v0 + v1;
    __syncthreads();
    for (int off = 128; off > 0; off >>= 1) {
        if (tid < off) red[tid] += red[tid + off];
        __syncthreads();
    }
    float mean = red[0] * (1.0f / 512.0f);
    __syncthreads();
    float d0 = v0 - mean, d1 = v1 - mean;
    red[tid] = d0 * d0 + d1 * d1;
    __syncthreads();
    for (int off = 128; off > 0; off >>= 1) {
        if (tid < off) red[tid] += red[tid + off];
        __syncthreads();
    }
    float var = red[0] * (1.0f / 512.0f);
    float rs = rsqrtf(var + 1e-6f);
    h[row * 512 + tid] = d0 * rs;
    h[row * 512 + tid + 256] = d1 * rs;
}

// ---------------- generic tiled fp32 GEMM: C = [gelu](A@W + bias) [+ R] ----------------
// 64x64 tile, BK=16, 256 threads, 4x4 microtile. M,N multiples of 64; K multiple of 16.
template <bool GELU, bool RES, bool BIAS>
__global__ __launch_bounds__(256) void gemm_k(const float* __restrict__ A,
                                              const float* __restrict__ W,
                                              const float* __restrict__ bias,
                                              const float* __restrict__ R,
                                              float* __restrict__ C,
                                              int M, int N, int K) {
    __shared__ float As[16][65];   // As[k][m]
    __shared__ float Ws[16][68];   // Ws[k][n] (row stride 68 keeps float4 alignment)
    const int bm = blockIdx.y * 64;
    const int bn = blockIdx.x * 64;
    const int tid = threadIdx.x;
    const int tx = tid & 15, ty = tid >> 4;
    const int arow = tid >> 2;            // 0..63
    const int acol = (tid & 3) * 4;       // 0,4,8,12
    const int wrow = tid >> 4;            // 0..15
    const int wcol = (tid & 15) * 4;      // 0..60
    float acc[4][4] = {};
    for (int k0 = 0; k0 < K; k0 += 16) {
        float4 av = *(const float4*)&A[(bm + arow) * K + k0 + acol];
        float4 wv = *(const float4*)&W[(k0 + wrow) * N + bn + wcol];
        __syncthreads();
        As[acol + 0][arow] = av.x;
        As[acol + 1][arow] = av.y;
        As[acol + 2][arow] = av.z;
        As[acol + 3][arow] = av.w;
        *(float4*)&Ws[wrow][wcol] = wv;
        __syncthreads();
#pragma unroll
        for (int kk = 0; kk < 16; ++kk) {
            float a0 = As[kk][ty * 4 + 0], a1 = As[kk][ty * 4 + 1];
            float a2 = As[kk][ty * 4 + 2], a3 = As[kk][ty * 4 + 3];
            float b0 = Ws[kk][tx * 4 + 0], b1 = Ws[kk][tx * 4 + 1];
            float b2 = Ws[kk][tx * 4 + 2], b3 = Ws[kk][tx * 4 + 3];
            acc[0][0] += a0 * b0; acc[0][1] += a0 * b1; acc[0][2] += a0 * b2; acc[0][3] += a0 * b3;
            acc[1][0] += a1 * b0; acc[1][1] += a1 * b1; acc[1][2] += a1 * b2; acc[1][3] += a1 * b3;
            acc[2][0] += a2 * b0; acc[2][1] += a2 * b1; acc[2][2] += a2 * b2; acc[2][3] += a2 * b3;
            acc[3][0] += a3 * b0; acc[3][1] += a3 * b1; acc[3][2] += a3 * b2; acc[3][3] += a3 * b3;
        }
    }
#pragma unroll
    for (int u = 0; u < 4; ++u) {
        int r = bm + ty * 4 + u;
#pragma unroll
        for (int v = 0; v < 4; ++v) {
            int c = bn + tx * 4 + v;
            float val = acc[u][v];
            if (BIAS) val += bias[c];
            if (GELU) val = gelu_f(val);
            if (RES) val += R[r * N + c];
            C[r * N + c] = val;
        }
    }
}

// ---------------- attention scores: S[b,h,t,j] = (Q[t]·K[j])*0.125 or -inf ----------------
__global__ __launch_bounds__(256) void scores_k(const float* __restrict__ Q,
                                                const float* __restrict__ K,
                                                const float* __restrict__ tsym,
                                                float* __restrict__ S) {
    int idx = blockIdx.x * 256 + threadIdx.x;   // B*NH*N*N = 524288
    int j = idx & 127;
    int t = (idx >> 7) & 127;
    int hh = (idx >> 14) & 7;
    int b = idx >> 17;
    float s;
    if (tsym[(b << 14) + (t << 7) + j] > 0.0f) {
        const float* q = Q + ((b * 128 + t) * 512) + hh * 64;
        const float* k = K + ((b * 128 + j) * 512) + hh * 64;
        float acc = 0.0f;
#pragma unroll 8
        for (int d = 0; d < 64; ++d) acc += q[d] * k[d];
        s = acc * 0.125f;
    } else {
        s = -INFINITY;
    }
    S[idx] = s;
}

// ---------------- softmax over last dim (128), one wave per row, in place ----------------
__global__ __launch_bounds__(64) void softmax_k(float* __restrict__ S) {
    int row = blockIdx.x;                       // B*NH*N = 4096
    float* s = S + row * 128;
    int lane = threadIdx.x;
    float s0 = s[lane], s1 = s[lane + 64];
    float m = fmaxf(s0, s1);
#pragma unroll
    for (int off = 32; off > 0; off >>= 1) m = fmaxf(m, __shfl_xor(m, off));
    if (m == -INFINITY) {                       // no incoming edges
        s[lane] = 0.0f; s[lane + 64] = 0.0f;
        return;
    }
    float e0 = __expf(s0 - m) * (s0 == -INFINITY ? 0.0f : 1.0f);
    float e1 = __expf(s1 - m) * (s1 == -INFINITY ? 0.0f : 1.0f);
    // expf(-inf) is 0 anyway; the multiply guards against NaN paranoia only.
    float d = e0 + e1;
#pragma unroll
    for (int off = 32; off > 0; off >>= 1) d += __shfl_xor(d, off);
    d += 1e-12f;
    s[lane] = e0 / d;
    s[lane + 64] = e1 / d;
}

// ---------------- agg[t, h*64+d] = sum_j A[b,h,t,j] * V[b*128+j, h*64+d] ----------------
__global__ __launch_bounds__(256) void agg_k(const float* __restrict__ S,
                                             const float* __restrict__ V,
                                             float* __restrict__ agg) {
    int idx = blockIdx.x * 256 + threadIdx.x;   // TN*H = 262144
    int col = idx & 511;
    int t = idx >> 9;                           // global row 0..511
    int b = t >> 7;
    int hh = col >> 6;
    const float* arow = S + (((b * 8 + hh) * 128 + (t & 127)) * 128);
    const float* v = V + (b * 128) * 512 + col;
    float acc = 0.0f;
#pragma unroll 8
    for (int j = 0; j < 128; ++j) acc += arow[j] * v[j * 512];
    agg[idx] = acc;
}

// ---------------- per-edge final MLP -> sigmoid, one wave (block=64) per edge ----------------
__global__ __launch_bounds__(64) void edge_k(const int* __restrict__ ei, int E,
                                             const float* __restrict__ x,
                                             const float* __restrict__ ae,
                                             const float* __restrict__ be,
                                             const float* __restrict__ ew1,
                                             const float* __restrict__ ew2,
                                             const float* __restrict__ eb2,
                                             const float* __restrict__ ew3,
                                             const float* __restrict__ eb3,
                                             float* __restrict__ P) {
    int e = blockIdx.x;
    int lane = threadIdx.x;
    int src = ei[e];          // i + b*N
    int dst = ei[E + e];      // j + b*N
    int b = src >> 7;
    int i = src & 127;
    int j = dst & 127;
    __shared__ float prod[512];
    __shared__ float g1s[64];
    const float* xi = x + src * 512;
    const float* xj = x + dst * 512;
#pragma unroll
    for (int u = 0; u < 8; ++u) {
        int m = lane + 64 * u;
        prod[m] = xi[m] * xj[m];
    }
    __syncthreads();
    const float* w1c = ew1 + 1024 * 64;
    float c = 0.0f;
#pragma unroll 4
    for (int m = 0; m < 512; ++m) c += prod[m] * w1c[m * 64 + lane];
    float g1 = gelu_f(c + ae[src * 64 + lane] + be[dst * 64 + lane]);
    g1s[lane] = g1;
    __syncthreads();
    float g2 = eb2[lane];
#pragma unroll 8
    for (int m = 0; m < 64; ++m) g2 += g1s[m] * ew2[m * 64 + lane];
    g2 = gelu_f(g2);
    float v = g2 * ew3[lane];
#pragma unroll
    for (int off = 32; off > 0; off >>= 1) v += __shfl_xor(v, off);
    if (lane == 0) {
        float val = v + eb3[0];
        P[(b << 14) + (i << 7) + j] = 1.0f / (1.0f + expf(-val));
    }
}

// ---------------- final: out = mask * 0.5*(P + P^T), zero diagonal ----------------
__global__ __launch_bounds__(256) void final_k(const float* __restrict__ tsym,
                                               const float* __restrict__ P,
                                               float* __restrict__ out) {
    int idx = blockIdx.x * 256 + threadIdx.x;   // 65536
    int b = idx >> 14, i = (idx >> 7) & 127, j = idx & 127;
    float o = 0.0f;
    if (i != j && tsym[idx] > 0.0f)
        o = 0.5f * (P[idx] + P[(b << 14) + (j << 7) + i]);
    out[idx] = o;
}

extern "C" void kernel_launch(void* const* d_in, const int* in_sizes, int n_in,
                              void* d_out, int out_size, void* d_ws, size_t ws_size,
                              hipStream_t stream) {
    const float* topo   = (const float*)d_in[0];
    const float* weight = (const float*)d_in[1];
    const int*   ei     = (const int*)d_in[2];
    const float* w_topo = (const float*)d_in[3];
    const float* b_topo = (const float*)d_in[4];
    const float* w_w    = (const float*)d_in[5];
    const float* b_w    = (const float*)d_in[6];
    const float* n_emb  = (const float*)d_in[7];
    const float* wq = (const float*)d_in[8];  const float* bq = (const float*)d_in[9];
    const float* wk = (const float*)d_in[10]; const float* bk = (const float*)d_in[11];
    const float* wv = (const float*)d_in[12]; const float* bv = (const float*)d_in[13];
    const float* wo = (const float*)d_in[14]; const float* bo = (const float*)d_in[15];
    const float* w1 = (const float*)d_in[16]; const float* b1 = (const float*)d_in[17];
    const float* w2 = (const float*)d_in[18]; const float* b2 = (const float*)d_in[19];
    const float* ew1 = (const float*)d_in[20]; const float* eb1 = (const float*)d_in[21];
    const float* ew2 = (const float*)d_in[22]; const float* eb2 = (const float*)d_in[23];
    const float* ew3 = (const float*)d_in[24]; const float* eb3 = (const float*)d_in[25];
    const int E = in_sizes[2] / 2;

    float* w = (float*)d_ws;
    float* tsym = w;                    // 65536
    float* x    = tsym + 65536;         // 262144
    float* h    = x + 262144;           // 262144
    float* Q    = h + 262144;           // 262144
    float* Kt   = Q + 262144;           // 262144
    float* V    = Kt + 262144;          // 262144
    float* agg  = V + 262144;           // 262144
    float* mid  = agg + 262144;         // 1048576 (also aliased as S: 524288)
    float* S    = mid;
    float* ae   = mid + 1048576;        // 32768
    float* be   = ae + 32768;           // 32768
    float* P    = be + 32768;           // 65536

    tsym_k<<<256, 256, 0, stream>>>(topo, tsym);
    x0_k<<<1024, 256, 0, stream>>>(tsym, w_topo, b_topo, weight, w_w, b_w, n_emb, x);

    dim3 g512(512 / 64, 512 / 64);
    dim3 gmlp1(2048 / 64, 512 / 64);
    dim3 gedge(64 / 64, 512 / 64);

    for (int d = 0; d < 4; ++d) {
        const float* wqd = wq + d * 512 * 512; const float* bqd = bq + d * 512;
        const float* wkd = wk + d * 512 * 512; const float* bkd = bk + d * 512;
        const float* wvd = wv + d * 512 * 512; const float* bvd = bv + d * 512;
        const float* wod = wo + d * 512 * 512; const float* bod = bo + d * 512;
        const float* w1d = w1 + d * 512 * 2048; const float* b1d = b1 + d * 2048;
        const float* w2d = w2 + d * 2048 * 512; const float* b2d = b2 + d * 512;

        ln_k<<<512, 256, 0, stream>>>(x, h);
        gemm_k<false, false, true><<<g512, 256, 0, stream>>>(h, wqd, bqd, nullptr, Q, 512, 512, 512);
        gemm_k<false, false, true><<<g512, 256, 0, stream>>>(h, wkd, bkd, nullptr, Kt, 512, 512, 512);
        gemm_k<false, false, true><<<g512, 256, 0, stream>>>(h, wvd, bvd, nullptr, V, 512, 512, 512);
        scores_k<<<2048, 256, 0, stream>>>(Q, Kt, tsym, S);
        softmax_k<<<4096, 64, 0, stream>>>(S);
        agg_k<<<1024, 256, 0, stream>>>(S, V, agg);
        gemm_k<false, true, true><<<g512, 256, 0, stream>>>(agg, wod, bod, x, x, 512, 512, 512);
        ln_k<<<512, 256, 0, stream>>>(x, h);
        gemm_k<true, false, true><<<gmlp1, 256, 0, stream>>>(h, w1d, b1d, nullptr, mid, 512, 2048, 512);
        gemm_k<false, true, true><<<g512, 256, 0, stream>>>(mid, w2d, b2d, x, x, 512, 512, 2048);
    }

    // edge-final MLP: per-node terms then per-edge cross term
    gemm_k<false, false, true><<<gedge, 256, 0, stream>>>(x, ew1, eb1, nullptr, ae, 512, 64, 512);
    gemm_k<false, false, false><<<gedge, 256, 0, stream>>>(x, ew1 + 512 * 64, nullptr, nullptr, be, 512, 64, 512);
    edge_k<<<E, 64, 0, stream>>>(ei, E, x, ae, be, ew1, ew2, eb2, ew3, eb3, P);
    final_k<<<256, 256, 0, stream>>>(tsym, P, (float*)d_out);
}

// Round 2
// 662.136 us; speedup vs baseline: 2.0840x; 2.0840x over previous
//
#include <hip/hip_runtime.h>
#include <hip/hip_bf16.h>
#include <math.h>

typedef __attribute__((ext_vector_type(8))) short bf16x8;
typedef __attribute__((ext_vector_type(4))) float f32x4;
typedef unsigned short u16;

__device__ __forceinline__ float gelu_f(float x) {
    float x3 = x * x * x;
    return 0.5f * x * (1.0f + tanhf(0.7978845608028654f * (x + 0.044715f * x3)));
}
__device__ __forceinline__ void bf_split(float v, u16& hi, u16& lo) {
    __hip_bfloat16 h = __float2bfloat16(v);
    hi = *(u16*)&h;
    float r = v - __bfloat162float(h);
    __hip_bfloat16 l = __float2bfloat16(r);
    lo = *(u16*)&l;
}

// ---------------- tsym = topo + topo^T ----------------
__global__ __launch_bounds__(256) void tsym_k(const float* __restrict__ topo,
                                              float* __restrict__ tsym) {
    int idx = blockIdx.x * 256 + threadIdx.x;
    int b = idx >> 14, i = (idx >> 7) & 127, j = idx & 127;
    tsym[idx] = topo[idx] + topo[(b << 14) + (j << 7) + i];
}

// ---------------- x0 ----------------
__global__ __launch_bounds__(256) void x0_k(const float* __restrict__ tsym,
                                            const float* __restrict__ w_topo,
                                            const float* __restrict__ b_topo,
                                            const float* __restrict__ weight,
                                            const float* __restrict__ w_w,
                                            const float* __restrict__ b_w,
                                            const float* __restrict__ n_emb,
                                            float* __restrict__ x) {
    int idx = blockIdx.x * 256 + threadIdx.x;
    int hcol = idx & 511;
    int bn = idx >> 9;
    int n = bn & 127;
    const float* trow = tsym + bn * 128;
    float acc = 0.0f;
#pragma unroll 8
    for (int m = 0; m < 128; ++m) acc += trow[m] * w_topo[m * 512 + hcol];
    acc += b_topo[hcol] + weight[bn] * w_w[hcol] + b_w[hcol] + n_emb[n * 512 + hcol];
    x[idx] = acc;
}

// ---------------- LayerNorm -> split bf16 ----------------
__global__ __launch_bounds__(256) void ln_k(const float* __restrict__ x,
                                            u16* __restrict__ hhi, u16* __restrict__ hlo) {
    int row = blockIdx.x;
    int tid = threadIdx.x;
    const float* xr = x + row * 512;
    float v0 = xr[tid], v1 = xr[tid + 256];
    __shared__ float red[256];
    red[tid] = v0 + v1;
    __syncthreads();
    for (int off = 128; off > 0; off >>= 1) {
        if (tid < off) red[tid] += red[tid + off];
        __syncthreads();
    }
    float mean = red[0] * (1.0f / 512.0f);
    __syncthreads();
    float d0 = v0 - mean, d1 = v1 - mean;
    red[tid] = d0 * d0 + d1 * d1;
    __syncthreads();
    for (int off = 128; off > 0; off >>= 1) {
        if (tid < off) red[tid] += red[tid + off];
        __syncthreads();
    }
    float var = red[0] * (1.0f / 512.0f);
    float rs = rsqrtf(var + 1e-6f);
    u16 h, l;
    bf_split(d0 * rs, h, l); hhi[row * 512 + tid] = h; hlo[row * 512 + tid] = l;
    bf_split(d1 * rs, h, l); hhi[row * 512 + tid + 256] = h; hlo[row * 512 + tid + 256] = l;
}

// ---------------- weight transpose + bf16-split prep ----------------
// dst layouts are [N][K] bf16 hi/lo. 64x64 tiles via LDS.
__global__ __launch_bounds__(256) void prep_k(
    const float* __restrict__ wq, const float* __restrict__ wk, const float* __restrict__ wv,
    const float* __restrict__ wo, const float* __restrict__ w1, const float* __restrict__ w2,
    const float* __restrict__ ew1,
    u16* __restrict__ qkvt_h, u16* __restrict__ qkvt_l,
    u16* __restrict__ wot_h, u16* __restrict__ wot_l,
    u16* __restrict__ w1t_h, u16* __restrict__ w1t_l,
    u16* __restrict__ w2t_h, u16* __restrict__ w2t_l,
    u16* __restrict__ eabt_h, u16* __restrict__ eabt_l,
    u16* __restrict__ ect_h, u16* __restrict__ ect_l) {
    __shared__ u16 Hs[64][68];
    __shared__ u16 Ls[64][68];
    int bid = blockIdx.x;
    int region, tr, KK;
    u16 *dh, *dl;
    if (bid < 768)       { region = 0; tr = bid;        KK = 512;  dh = qkvt_h; dl = qkvt_l; }
    else if (bid < 1024) { region = 1; tr = bid - 768;  KK = 512;  dh = wot_h;  dl = wot_l; }
    else if (bid < 2048) { region = 2; tr = bid - 1024; KK = 512;  dh = w1t_h;  dl = w1t_l; }
    else if (bid < 3072) { region = 3; tr = bid - 2048; KK = 2048; dh = w2t_h;  dl = w2t_l; }
    else if (bid < 3088) { region = 4; tr = bid - 3072; KK = 512;  dh = eabt_h; dl = eabt_l; }
    else                 { region = 5; tr = bid - 3088; KK = 512;  dh = ect_h;  dl = ect_l; }
    int ktiles = KK >> 6;
    int tn = tr / ktiles, tk = tr % ktiles;
    int k0 = tk * 64, n0g = tn * 64;
    int tid = threadIdx.x;
#pragma unroll
    for (int p = 0; p < 4; ++p) {
        int kk = p * 16 + (tid >> 4);
        int nn = (tid & 15) * 4;
        int kg = k0 + kk, ng = n0g + nn;
        const float* src;
        if (region == 0) {
            int d = ng / 1536; int nr = ng - d * 1536; int sel = nr >> 9; int nc = nr & 511;
            const float* w = sel == 0 ? wq : (sel == 1 ? wk : wv);
            src = w + ((size_t)(d * 512 + kg)) * 512 + nc;
        } else if (region == 1) {
            int d = ng >> 9; int nc = ng & 511;
            src = wo + ((size_t)(d * 512 + kg)) * 512 + nc;
        } else if (region == 2) {
            int d = ng >> 11; int nc = ng & 2047;
            src = w1 + ((size_t)(d * 512 + kg)) * 2048 + nc;
        } else if (region == 3) {
            int d = ng >> 9; int nc = ng & 511;
            src = w2 + ((size_t)(d * 2048 + kg)) * 512 + nc;
        } else if (region == 4) {
            src = (ng < 64) ? (ew1 + (size_t)kg * 64 + ng) : (ew1 + (size_t)(512 + kg) * 64 + (ng - 64));
        } else {
            src = ew1 + (size_t)(1024 + kg) * 64 + ng;
        }
        float4 v = *(const float4*)src;
        u16 h0, l0, h1, l1, h2, l2, h3, l3;
        bf_split(v.x, h0, l0); bf_split(v.y, h1, l1);
        bf_split(v.z, h2, l2); bf_split(v.w, h3, l3);
        *(ushort4*)&Hs[kk][nn] = make_ushort4(h0, h1, h2, h3);
        *(ushort4*)&Ls[kk][nn] = make_ushort4(l0, l1, l2, l3);
    }
    __syncthreads();
#pragma unroll
    for (int p = 0; p < 2; ++p) {
        int chunk = p * 256 + tid;
        int nl = chunk >> 3;
        int k8 = (chunk & 7) * 8;
        ushort4 ha, hb, la, lb;
        ha.x = Hs[k8 + 0][nl]; ha.y = Hs[k8 + 1][nl]; ha.z = Hs[k8 + 2][nl]; ha.w = Hs[k8 + 3][nl];
        hb.x = Hs[k8 + 4][nl]; hb.y = Hs[k8 + 5][nl]; hb.z = Hs[k8 + 6][nl]; hb.w = Hs[k8 + 7][nl];
        la.x = Ls[k8 + 0][nl]; la.y = Ls[k8 + 1][nl]; la.z = Ls[k8 + 2][nl]; la.w = Ls[k8 + 3][nl];
        lb.x = Ls[k8 + 4][nl]; lb.y = Ls[k8 + 5][nl]; lb.z = Ls[k8 + 6][nl]; lb.w = Ls[k8 + 7][nl];
        size_t dst = (size_t)(n0g + nl) * KK + k0 + k8;
        *(ushort4*)(dh + dst) = ha; *(ushort4*)(dh + dst + 4) = hb;
        *(ushort4*)(dl + dst) = la; *(ushort4*)(dl + dst + 4) = lb;
    }
}

// ---------------- small bias concat prep ----------------
__global__ __launch_bounds__(256) void bias_k(const float* __restrict__ bq, const float* __restrict__ bk,
                                              const float* __restrict__ bv, const float* __restrict__ eb1,
                                              float* __restrict__ qkvb, float* __restrict__ ebias) {
    int i = blockIdx.x * 256 + threadIdx.x;
    if (i < 6144) {
        int d = i / 1536, r = i - d * 1536; int sel = r >> 9, c = r & 511;
        const float* s = sel == 0 ? bq : (sel == 1 ? bk : bv);
        qkvb[i] = s[d * 512 + c];
    } else if (i < 6272) {
        int j = i - 6144;
        ebias[j] = j < 64 ? eb1[j] : 0.0f;
    }
}

// ---------------- split-bf16 MFMA GEMM: C = [gelu](Ahi/lo @ Wt + bias) [+R], opt split out ----------------
// grid(N/64, M/32), 256 threads (4 waves); W is [N][K] bf16 hi/lo.
template <bool GELU, bool RES, bool OUTF, bool OUTS>
__global__ __launch_bounds__(256) void mgemm(
    const u16* __restrict__ Ahi, const u16* __restrict__ Alo,
    const u16* __restrict__ Whi, const u16* __restrict__ Wlo,
    const float* __restrict__ bias, const float* __restrict__ Rres,
    float* __restrict__ C, u16* __restrict__ Chi, u16* __restrict__ Clo,
    int M, int N, int K) {
    int lane = threadIdx.x & 63;
    int w = threadIdx.x >> 6;
    int m0 = blockIdx.y * 32 + (w & 1) * 16;
    int n0 = blockIdx.x * 64 + (w >> 1) * 32;
    int l15 = lane & 15;
    int kq = (lane >> 4) * 8;
    const u16* pAh = Ahi + (size_t)(m0 + l15) * K + kq;
    const u16* pAl = Alo + (size_t)(m0 + l15) * K + kq;
    const u16* pB1h = Whi + (size_t)(n0 + l15) * K + kq;
    const u16* pB1l = Wlo + (size_t)(n0 + l15) * K + kq;
    const u16* pB2h = Whi + (size_t)(n0 + 16 + l15) * K + kq;
    const u16* pB2l = Wlo + (size_t)(n0 + 16 + l15) * K + kq;
    f32x4 acc0 = {0.f, 0.f, 0.f, 0.f}, acc1 = {0.f, 0.f, 0.f, 0.f};
    for (int k0 = 0; k0 < K; k0 += 32) {
        bf16x8 ah = *(const bf16x8*)(pAh + k0);
        bf16x8 al = *(const bf16x8*)(pAl + k0);
        bf16x8 b1h = *(const bf16x8*)(pB1h + k0);
        bf16x8 b1l = *(const bf16x8*)(pB1l + k0);
        bf16x8 b2h = *(const bf16x8*)(pB2h + k0);
        bf16x8 b2l = *(const bf16x8*)(pB2l + k0);
        acc0 = __builtin_amdgcn_mfma_f32_16x16x32_bf16(ah, b1h, acc0, 0, 0, 0);
        acc1 = __builtin_amdgcn_mfma_f32_16x16x32_bf16(ah, b2h, acc1, 0, 0, 0);
        acc0 = __builtin_amdgcn_mfma_f32_16x16x32_bf16(ah, b1l, acc0, 0, 0, 0);
        acc1 = __builtin_amdgcn_mfma_f32_16x16x32_bf16(ah, b2l, acc1, 0, 0, 0);
        acc0 = __builtin_amdgcn_mfma_f32_16x16x32_bf16(al, b1h, acc0, 0, 0, 0);
        acc1 = __builtin_amdgcn_mfma_f32_16x16x32_bf16(al, b2h, acc1, 0, 0, 0);
    }
    int rbase = m0 + (lane >> 4) * 4;
#pragma unroll
    for (int f = 0; f < 2; ++f) {
        f32x4 a = f ? acc1 : acc0;
        int col = n0 + f * 16 + l15;
        float bv = bias[col];
#pragma unroll
        for (int r = 0; r < 4; ++r) {
            int row = rbase + r;
            float val = a[r] + bv;
            if (GELU) val = gelu_f(val);
            if (RES) val += Rres[(size_t)row * N + col];
            if (OUTF) C[(size_t)row * N + col] = val;
            if (OUTS) {
                u16 h, l; bf_split(val, h, l);
                Chi[(size_t)row * N + col] = h; Clo[(size_t)row * N + col] = l;
            }
        }
    }
}

// ---------------- fused masked attention per (b, head, 16-row tile) ----------------
__global__ __launch_bounds__(256) void attn_k(const float* __restrict__ qkv,
                                              const float* __restrict__ tsym,
                                              u16* __restrict__ agghi, u16* __restrict__ agglo) {
    int tt = blockIdx.x, hh = blockIdx.y, b = blockIdx.z;
    __shared__ __align__(16) float Ks[128 * 68];
    __shared__ __align__(16) float Vt[64 * 132];
    __shared__ __align__(16) float Ss[16 * 132];
    int tid = threadIdx.x;
    {
        int j = tid >> 1, c0 = (tid & 1) * 32;
        const float* kr = qkv + ((size_t)(b * 128 + j)) * 1536 + 512 + hh * 64 + c0;
        const float* vr = kr + 512;
#pragma unroll
        for (int c = 0; c < 32; c += 4) {
            float4 kv = *(const float4*)(kr + c);
            float4 vv = *(const float4*)(vr + c);
            Ks[j * 68 + c0 + c + 0] = kv.x; Ks[j * 68 + c0 + c + 1] = kv.y;
            Ks[j * 68 + c0 + c + 2] = kv.z; Ks[j * 68 + c0 + c + 3] = kv.w;
            Vt[(c0 + c + 0) * 132 + j] = vv.x; Vt[(c0 + c + 1) * 132 + j] = vv.y;
            Vt[(c0 + c + 2) * 132 + j] = vv.z; Vt[(c0 + c + 3) * 132 + j] = vv.w;
        }
    }
    __syncthreads();
    {
        int j = tid & 127, th = tid >> 7;
        const float* qrow = qkv + ((size_t)(b * 128 + tt * 16 + th * 8)) * 1536 + hh * 64;
        float acc[8] = {0.f, 0.f, 0.f, 0.f, 0.f, 0.f, 0.f, 0.f};
        for (int d0 = 0; d0 < 64; d0 += 4) {
            float4 kv = *(const float4*)&Ks[j * 68 + d0];
#pragma unroll
            for (int r = 0; r < 8; ++r) {
                float4 qv = *(const float4*)(qrow + (size_t)r * 1536 + d0);
                acc[r] += qv.x * kv.x + qv.y * kv.y + qv.z * kv.z + qv.w * kv.w;
            }
        }
        const float* tsr = tsym + ((size_t)b << 14) + (size_t)(tt * 16 + th * 8) * 128 + j;
#pragma unroll
        for (int r = 0; r < 8; ++r) {
            int t = th * 8 + r;
            float sv = (tsr[r * 128] > 0.f) ? acc[r] * 0.125f : -INFINITY;
            Ss[t * 132 + j] = sv;
        }
    }
    __syncthreads();
    {
        int row = tid >> 4, l16 = tid & 15;
        float v[8]; float m = -INFINITY;
#pragma unroll
        for (int c = 0; c < 8; ++c) { v[c] = Ss[row * 132 + l16 + c * 16]; m = fmaxf(m, v[c]); }
#pragma unroll
        for (int off = 8; off; off >>= 1) m = fmaxf(m, __shfl_xor(m, off));
        float ssum = 0.f;
#pragma unroll
        for (int c = 0; c < 8; ++c) {
            float e = (v[c] == -INFINITY) ? 0.f : __expf(v[c] - m);
            v[c] = e; ssum += e;
        }
#pragma unroll
        for (int off = 8; off; off >>= 1) ssum += __shfl_xor(ssum, off);
        float inv = 1.0f / (ssum + 1e-12f);
#pragma unroll
        for (int c = 0; c < 8; ++c) Ss[row * 132 + l16 + c * 16] = v[c] * inv;
    }
    __syncthreads();
    {
        int d = tid & 63, tq = tid >> 6;
        float a0 = 0.f, a1 = 0.f, a2 = 0.f, a3 = 0.f;
        for (int j0 = 0; j0 < 128; j0 += 4) {
            float4 vv = *(const float4*)&Vt[d * 132 + j0];
            float4 s0 = *(const float4*)&Ss[(tq * 4 + 0) * 132 + j0];
            float4 s1 = *(const float4*)&Ss[(tq * 4 + 1) * 132 + j0];
            float4 s2 = *(const float4*)&Ss[(tq * 4 + 2) * 132 + j0];
            float4 s3 = *(const float4*)&Ss[(tq * 4 + 3) * 132 + j0];
            a0 += s0.x * vv.x + s0.y * vv.y + s0.z * vv.z + s0.w * vv.w;
            a1 += s1.x * vv.x + s1.y * vv.y + s1.z * vv.z + s1.w * vv.w;
            a2 += s2.x * vv.x + s2.y * vv.y + s2.z * vv.z + s2.w * vv.w;
            a3 += s3.x * vv.x + s3.y * vv.y + s3.z * vv.z + s3.w * vv.w;
        }
        float accv[4] = {a0, a1, a2, a3};
        int growbase = b * 128 + tt * 16;
#pragma unroll
        for (int i = 0; i < 4; ++i) {
            int t = tq * 4 + i;
            u16 h, l; bf_split(accv[i], h, l);
            size_t o = (size_t)(growbase + t) * 512 + hh * 64 + d;
            agghi[o] = h; agglo[o] = l;
        }
    }
}

// ---------------- fused per-edge MLP (cross-term MFMA + 2 dense layers + sigmoid) ----------------
__global__ __launch_bounds__(256) void edgemlp_k(const int* __restrict__ ei, int E,
                                                 const float* __restrict__ x,
                                                 const float* __restrict__ aebe,
                                                 const u16* __restrict__ ect_h, const u16* __restrict__ ect_l,
                                                 const float* __restrict__ ew2, const float* __restrict__ eb2,
                                                 const float* __restrict__ ew3, const float* __restrict__ eb3,
                                                 float* __restrict__ P) {
    __shared__ __align__(16) u16 Ph[32][40];
    __shared__ __align__(16) u16 Pl[32][40];
    __shared__ float G1[32][66];
    __shared__ float G2[32][66];
    __shared__ int s_src[32], s_dst[32];
    int tid = threadIdx.x;
    int e0 = blockIdx.x * 32;
    if (tid < 32) {
        int e = e0 + tid;
        s_src[tid] = e < E ? ei[e] : 0;
        s_dst[tid] = e < E ? ei[E + e] : 0;
    }
    __syncthreads();
    int lane = tid & 63, w = tid >> 6;
    int el = tid >> 3, kq = (tid & 7) * 4;
    const float* xi = x + (size_t)s_src[el] * 512;
    const float* xj = x + (size_t)s_dst[el] * 512;
    int l15 = lane & 15;
    int kf = (lane >> 4) * 8;
    int mf = (w & 1) * 16;
    int nf = (w >> 1) * 32;
    const u16* pB1h = ect_h + (size_t)(nf + l15) * 512 + kf;
    const u16* pB1l = ect_l + (size_t)(nf + l15) * 512 + kf;
    const u16* pB2h = ect_h + (size_t)(nf + 16 + l15) * 512 + kf;
    const u16* pB2l = ect_l + (size_t)(nf + 16 + l15) * 512 + kf;
    f32x4 acc0 = {0.f, 0.f, 0.f, 0.f}, acc1 = {0.f, 0.f, 0.f, 0.f};
    for (int k0 = 0; k0 < 512; k0 += 32) {
        float4 a = *(const float4*)(xi + k0 + kq);
        float4 bb = *(const float4*)(xj + k0 + kq);
        u16 h0, l0, h1, l1, h2, l2, h3, l3;
        bf_split(a.x * bb.x, h0, l0); bf_split(a.y * bb.y, h1, l1);
        bf_split(a.z * bb.z, h2, l2); bf_split(a.w * bb.w, h3, l3);
        __syncthreads();
        *(ushort4*)&Ph[el][kq] = make_ushort4(h0, h1, h2, h3);
        *(ushort4*)&Pl[el][kq] = make_ushort4(l0, l1, l2, l3);
        __syncthreads();
        bf16x8 ah = *(const bf16x8*)&Ph[mf + l15][kf];
        bf16x8 al = *(const bf16x8*)&Pl[mf + l15][kf];
        bf16x8 b1h = *(const bf16x8*)(pB1h + k0);
        bf16x8 b1l = *(const bf16x8*)(pB1l + k0);
        bf16x8 b2h = *(const bf16x8*)(pB2h + k0);
        bf16x8 b2l = *(const bf16x8*)(pB2l + k0);
        acc0 = __builtin_amdgcn_mfma_f32_16x16x32_bf16(ah, b1h, acc0, 0, 0, 0);
        acc1 = __builtin_amdgcn_mfma_f32_16x16x32_bf16(ah, b2h, acc1, 0, 0, 0);
        acc0 = __builtin_amdgcn_mfma_f32_16x16x32_bf16(ah, b1l, acc0, 0, 0, 0);
        acc1 = __builtin_amdgcn_mfma_f32_16x16x32_bf16(ah, b2l, acc1, 0, 0, 0);
        acc0 = __builtin_amdgcn_mfma_f32_16x16x32_bf16(al, b1h, acc0, 0, 0, 0);
        acc1 = __builtin_amdgcn_mfma_f32_16x16x32_bf16(al, b2h, acc1, 0, 0, 0);
    }
    int rb = mf + (lane >> 4) * 4;
#pragma unroll
    for (int f = 0; f < 2; ++f) {
        f32x4 a = f ? acc1 : acc0;
        int col = nf + f * 16 + l15;
#pragma unroll
        for (int r = 0; r < 4; ++r) {
            int e = rb + r;
            float c = a[r] + aebe[(size_t)s_src[e] * 128 + col] + aebe[(size_t)s_dst[e] * 128 + 64 + col];
            G1[e][col] = gelu_f(c);
        }
    }
    __syncthreads();
    {
        int col = tid & 63, eq = tid >> 6;
        float acc[8];
#pragma unroll
        for (int i = 0; i < 8; ++i) acc[i] = eb2[col];
        for (int m = 0; m < 64; ++m) {
            float wv = ew2[m * 64 + col];
#pragma unroll
            for (int i = 0; i < 8; ++i) acc[i] += G1[eq * 8 + i][m] * wv;
        }
#pragma unroll
        for (int i = 0; i < 8; ++i) G2[eq * 8 + i][col] = gelu_f(acc[i]);
    }
    __syncthreads();
    {
        int el2 = tid >> 3, c8 = (tid & 7) * 8;
        float p = 0.f;
#pragma unroll
        for (int i = 0; i < 8; ++i) p += G2[el2][c8 + i] * ew3[c8 + i];
        p += __shfl_xor(p, 1); p += __shfl_xor(p, 2); p += __shfl_xor(p, 4);
        if ((tid & 7) == 0 && e0 + el2 < E) {
            float logit = p + eb3[0];
            int s = s_src[el2], d2 = s_dst[el2];
            int bB = s >> 7, i2 = s & 127, j2 = d2 & 127;
            P[(bB << 14) + (i2 << 7) + j2] = 1.0f / (1.0f + expf(-logit));
        }
    }
}

// ---------------- final symmetrize + mask ----------------
__global__ __launch_bounds__(256) void final_k(const float* __restrict__ tsym,
                                               const float* __restrict__ P,
                                               float* __restrict__ out) {
    int idx = blockIdx.x * 256 + threadIdx.x;
    int b = idx >> 14, i = (idx >> 7) & 127, j = idx & 127;
    float o = 0.0f;
    if (i != j && tsym[idx] > 0.0f)
        o = 0.5f * (P[idx] + P[(b << 14) + (j << 7) + i]);
    out[idx] = o;
}

extern "C" void kernel_launch(void* const* d_in, const int* in_sizes, int n_in,
                              void* d_out, int out_size, void* d_ws, size_t ws_size,
                              hipStream_t stream) {
    const float* topo   = (const float*)d_in[0];
    const float* weight = (const float*)d_in[1];
    const int*   ei     = (const int*)d_in[2];
    const float* w_topo = (const float*)d_in[3];
    const float* b_topo = (const float*)d_in[4];
    const float* w_w    = (const float*)d_in[5];
    const float* b_w    = (const float*)d_in[6];
    const float* n_emb  = (const float*)d_in[7];
    const float* wq = (const float*)d_in[8];  const float* bq = (const float*)d_in[9];
    const float* wk = (const float*)d_in[10]; const float* bk = (const float*)d_in[11];
    const float* wv = (const float*)d_in[12]; const float* bv = (const float*)d_in[13];
    const float* wo = (const float*)d_in[14]; const float* bo = (const float*)d_in[15];
    const float* w1 = (const float*)d_in[16]; const float* b1 = (const float*)d_in[17];
    const float* w2 = (const float*)d_in[18]; const float* b2 = (const float*)d_in[19];
    const float* ew1 = (const float*)d_in[20]; const float* eb1 = (const float*)d_in[21];
    const float* ew2 = (const float*)d_in[22]; const float* eb2 = (const float*)d_in[23];
    const float* ew3 = (const float*)d_in[24]; const float* eb3 = (const float*)d_in[25];
    const int E = in_sizes[2] / 2;

    char* base = (char*)d_ws;
    size_t off = 0;
    auto alloc = [&](size_t bytes) { char* p = base + off; off += (bytes + 255) & ~(size_t)255; return p; };
    u16* qkvt_h = (u16*)alloc(3145728 * 2); u16* qkvt_l = (u16*)alloc(3145728 * 2);
    u16* wot_h  = (u16*)alloc(1048576 * 2); u16* wot_l  = (u16*)alloc(1048576 * 2);
    u16* w1t_h  = (u16*)alloc(4194304 * 2); u16* w1t_l  = (u16*)alloc(4194304 * 2);
    u16* w2t_h  = (u16*)alloc(4194304 * 2); u16* w2t_l  = (u16*)alloc(4194304 * 2);
    u16* eabt_h = (u16*)alloc(65536 * 2);   u16* eabt_l = (u16*)alloc(65536 * 2);
    u16* ect_h  = (u16*)alloc(32768 * 2);   u16* ect_l  = (u16*)alloc(32768 * 2);
    u16* h_hi   = (u16*)alloc(262144 * 2);  u16* h_lo   = (u16*)alloc(262144 * 2);
    u16* agg_hi = (u16*)alloc(262144 * 2);  u16* agg_lo = (u16*)alloc(262144 * 2);
    u16* mid_hi = (u16*)alloc(1048576 * 2); u16* mid_lo = (u16*)alloc(1048576 * 2);
    u16* x_hi   = (u16*)alloc(262144 * 2);  u16* x_lo   = (u16*)alloc(262144 * 2);
    float* qkvb  = (float*)alloc(6144 * 4);
    float* ebias = (float*)alloc(128 * 4);
    float* tsym  = (float*)alloc(65536 * 4);
    float* x     = (float*)alloc(262144 * 4);
    float* qkvo  = (float*)alloc(786432 * 4);
    float* aebe  = (float*)alloc(65536 * 4);
    float* P     = (float*)alloc(65536 * 4);

    prep_k<<<3096, 256, 0, stream>>>(wq, wk, wv, wo, w1, w2, ew1,
                                     qkvt_h, qkvt_l, wot_h, wot_l, w1t_h, w1t_l,
                                     w2t_h, w2t_l, eabt_h, eabt_l, ect_h, ect_l);
    bias_k<<<25, 256, 0, stream>>>(bq, bk, bv, eb1, qkvb, ebias);
    tsym_k<<<256, 256, 0, stream>>>(topo, tsym);
    x0_k<<<1024, 256, 0, stream>>>(tsym, w_topo, b_topo, weight, w_w, b_w, n_emb, x);

    for (int d = 0; d < 4; ++d) {
        ln_k<<<512, 256, 0, stream>>>(x, h_hi, h_lo);
        mgemm<false, false, true, false><<<dim3(24, 16), 256, 0, stream>>>(
            h_hi, h_lo, qkvt_h + (size_t)d * 1536 * 512, qkvt_l + (size_t)d * 1536 * 512,
            qkvb + d * 1536, nullptr, qkvo, nullptr, nullptr, 512, 1536, 512);
        attn_k<<<dim3(8, 8, 4), 256, 0, stream>>>(qkvo, tsym, agg_hi, agg_lo);
        mgemm<false, true, true, false><<<dim3(8, 16), 256, 0, stream>>>(
            agg_hi, agg_lo, wot_h + (size_t)d * 512 * 512, wot_l + (size_t)d * 512 * 512,
            bo + d * 512, x, x, nullptr, nullptr, 512, 512, 512);
        ln_k<<<512, 256, 0, stream>>>(x, h_hi, h_lo);
        mgemm<true, false, false, true><<<dim3(32, 16), 256, 0, stream>>>(
            h_hi, h_lo, w1t_h + (size_t)d * 2048 * 512, w1t_l + (size_t)d * 2048 * 512,
            b1 + d * 2048, nullptr, nullptr, mid_hi, mid_lo, 512, 2048, 512);
        if (d < 3) {
            mgemm<false, true, true, false><<<dim3(8, 16), 256, 0, stream>>>(
                mid_hi, mid_lo, w2t_h + (size_t)d * 512 * 2048, w2t_l + (size_t)d * 512 * 2048,
                b2 + d * 512, x, x, nullptr, nullptr, 512, 512, 2048);
        } else {
            mgemm<false, true, true, true><<<dim3(8, 16), 256, 0, stream>>>(
                mid_hi, mid_lo, w2t_h + (size_t)d * 512 * 2048, w2t_l + (size_t)d * 512 * 2048,
                b2 + d * 512, x, x, x_hi, x_lo, 512, 512, 2048);
        }
    }

    mgemm<false, false, true, false><<<dim3(2, 16), 256, 0, stream>>>(
        x_hi, x_lo, eabt_h, eabt_l, ebias, nullptr, aebe, nullptr, nullptr, 512, 128, 512);
    edgemlp_k<<<(E + 31) / 32, 256, 0, stream>>>(ei, E, x, aebe, ect_h, ect_l,
                                                 ew2, eb2, ew3, eb3, P);
    final_k<<<256, 256, 0, stream>>>(tsym, P, (float*)d_out);
}

// Round 3
// 318.774 us; speedup vs baseline: 4.3287x; 2.0771x over previous
//
#include <hip/hip_runtime.h>
#include <hip/hip_bf16.h>
#include <math.h>

typedef __attribute__((ext_vector_type(8))) short bf16x8;
typedef __attribute__((ext_vector_type(4))) float f32x4;
typedef unsigned short u16;

__device__ __forceinline__ float gelu_f(float x) {
    float x3 = x * x * x;
    return 0.5f * x * (1.0f + tanhf(0.7978845608028654f * (x + 0.044715f * x3)));
}
__device__ __forceinline__ void bf_split(float v, u16& hi, u16& lo) {
    __hip_bfloat16 h = __float2bfloat16(v);
    hi = *(u16*)&h;
    float r = v - __bfloat162float(h);
    __hip_bfloat16 l = __float2bfloat16(r);
    lo = *(u16*)&l;
}

// ---------------- tsym = topo + topo^T ----------------
__global__ __launch_bounds__(256) void tsym_k(const float* __restrict__ topo,
                                              float* __restrict__ tsym) {
    int idx = blockIdx.x * 256 + threadIdx.x;
    int b = idx >> 14, i = (idx >> 7) & 127, j = idx & 127;
    tsym[idx] = topo[idx] + topo[(b << 14) + (j << 7) + i];
}

// ---------------- x0 ----------------
__global__ __launch_bounds__(256) void x0_k(const float* __restrict__ tsym,
                                            const float* __restrict__ w_topo,
                                            const float* __restrict__ b_topo,
                                            const float* __restrict__ weight,
                                            const float* __restrict__ w_w,
                                            const float* __restrict__ b_w,
                                            const float* __restrict__ n_emb,
                                            float* __restrict__ x) {
    int idx = blockIdx.x * 256 + threadIdx.x;
    int hcol = idx & 511;
    int bn = idx >> 9;
    int n = bn & 127;
    const float* trow = tsym + bn * 128;
    float acc = 0.0f;
#pragma unroll 8
    for (int m = 0; m < 128; ++m) acc += trow[m] * w_topo[m * 512 + hcol];
    acc += b_topo[hcol] + weight[bn] * w_w[hcol] + b_w[hcol] + n_emb[n * 512 + hcol];
    x[idx] = acc;
}

// ---------------- LayerNorm -> split bf16 ----------------
__global__ __launch_bounds__(256) void ln_k(const float* __restrict__ x,
                                            u16* __restrict__ hhi, u16* __restrict__ hlo) {
    int row = blockIdx.x;
    int tid = threadIdx.x;
    const float* xr = x + row * 512;
    float v0 = xr[tid], v1 = xr[tid + 256];
    __shared__ float red[256];
    red[tid] = v0 + v1;
    __syncthreads();
    for (int off = 128; off > 0; off >>= 1) {
        if (tid < off) red[tid] += red[tid + off];
        __syncthreads();
    }
    float mean = red[0] * (1.0f / 512.0f);
    __syncthreads();
    float d0 = v0 - mean, d1 = v1 - mean;
    red[tid] = d0 * d0 + d1 * d1;
    __syncthreads();
    for (int off = 128; off > 0; off >>= 1) {
        if (tid < off) red[tid] += red[tid + off];
        __syncthreads();
    }
    float var = red[0] * (1.0f / 512.0f);
    float rs = rsqrtf(var + 1e-6f);
    u16 h, l;
    bf_split(d0 * rs, h, l); hhi[row * 512 + tid] = h; hlo[row * 512 + tid] = l;
    bf_split(d1 * rs, h, l); hhi[row * 512 + tid + 256] = h; hlo[row * 512 + tid + 256] = l;
}

// ---------------- weight transpose + bf16-split prep ----------------
__global__ __launch_bounds__(256) void prep_k(
    const float* __restrict__ wq, const float* __restrict__ wk, const float* __restrict__ wv,
    const float* __restrict__ wo, const float* __restrict__ w1, const float* __restrict__ w2,
    const float* __restrict__ ew1,
    u16* __restrict__ qkvt_h, u16* __restrict__ qkvt_l,
    u16* __restrict__ wot_h, u16* __restrict__ wot_l,
    u16* __restrict__ w1t_h, u16* __restrict__ w1t_l,
    u16* __restrict__ w2t_h, u16* __restrict__ w2t_l,
    u16* __restrict__ eabt_h, u16* __restrict__ eabt_l,
    u16* __restrict__ ect_h, u16* __restrict__ ect_l) {
    __shared__ u16 Hs[64][68];
    __shared__ u16 Ls[64][68];
    int bid = blockIdx.x;
    int region, tr, KK;
    u16 *dh, *dl;
    if (bid < 768)       { region = 0; tr = bid;        KK = 512;  dh = qkvt_h; dl = qkvt_l; }
    else if (bid < 1024) { region = 1; tr = bid - 768;  KK = 512;  dh = wot_h;  dl = wot_l; }
    else if (bid < 2048) { region = 2; tr = bid - 1024; KK = 512;  dh = w1t_h;  dl = w1t_l; }
    else if (bid < 3072) { region = 3; tr = bid - 2048; KK = 2048; dh = w2t_h;  dl = w2t_l; }
    else if (bid < 3088) { region = 4; tr = bid - 3072; KK = 512;  dh = eabt_h; dl = eabt_l; }
    else                 { region = 5; tr = bid - 3088; KK = 512;  dh = ect_h;  dl = ect_l; }
    int ktiles = KK >> 6;
    int tn = tr / ktiles, tk = tr % ktiles;
    int k0 = tk * 64, n0g = tn * 64;
    int tid = threadIdx.x;
#pragma unroll
    for (int p = 0; p < 4; ++p) {
        int kk = p * 16 + (tid >> 4);
        int nn = (tid & 15) * 4;
        int kg = k0 + kk, ng = n0g + nn;
        const float* src;
        if (region == 0) {
            int d = ng / 1536; int nr = ng - d * 1536; int sel = nr >> 9; int nc = nr & 511;
            const float* w = sel == 0 ? wq : (sel == 1 ? wk : wv);
            src = w + ((size_t)(d * 512 + kg)) * 512 + nc;
        } else if (region == 1) {
            int d = ng >> 9; int nc = ng & 511;
            src = wo + ((size_t)(d * 512 + kg)) * 512 + nc;
        } else if (region == 2) {
            int d = ng >> 11; int nc = ng & 2047;
            src = w1 + ((size_t)(d * 512 + kg)) * 2048 + nc;
        } else if (region == 3) {
            int d = ng >> 9; int nc = ng & 511;
            src = w2 + ((size_t)(d * 2048 + kg)) * 512 + nc;
        } else if (region == 4) {
            src = (ng < 64) ? (ew1 + (size_t)kg * 64 + ng) : (ew1 + (size_t)(512 + kg) * 64 + (ng - 64));
        } else {
            src = ew1 + (size_t)(1024 + kg) * 64 + ng;
        }
        float4 v = *(const float4*)src;
        u16 h0, l0, h1, l1, h2, l2, h3, l3;
        bf_split(v.x, h0, l0); bf_split(v.y, h1, l1);
        bf_split(v.z, h2, l2); bf_split(v.w, h3, l3);
        *(ushort4*)&Hs[kk][nn] = make_ushort4(h0, h1, h2, h3);
        *(ushort4*)&Ls[kk][nn] = make_ushort4(l0, l1, l2, l3);
    }
    __syncthreads();
#pragma unroll
    for (int p = 0; p < 2; ++p) {
        int chunk = p * 256 + tid;
        int nl = chunk >> 3;
        int k8 = (chunk & 7) * 8;
        ushort4 ha, hb, la, lb;
        ha.x = Hs[k8 + 0][nl]; ha.y = Hs[k8 + 1][nl]; ha.z = Hs[k8 + 2][nl]; ha.w = Hs[k8 + 3][nl];
        hb.x = Hs[k8 + 4][nl]; hb.y = Hs[k8 + 5][nl]; hb.z = Hs[k8 + 6][nl]; hb.w = Hs[k8 + 7][nl];
        la.x = Ls[k8 + 0][nl]; la.y = Ls[k8 + 1][nl]; la.z = Ls[k8 + 2][nl]; la.w = Ls[k8 + 3][nl];
        lb.x = Ls[k8 + 4][nl]; lb.y = Ls[k8 + 5][nl]; lb.z = Ls[k8 + 6][nl]; lb.w = Ls[k8 + 7][nl];
        size_t dst = (size_t)(n0g + nl) * KK + k0 + k8;
        *(ushort4*)(dh + dst) = ha; *(ushort4*)(dh + dst + 4) = hb;
        *(ushort4*)(dl + dst) = la; *(ushort4*)(dl + dst + 4) = lb;
    }
}

// ---------------- small bias concat prep ----------------
__global__ __launch_bounds__(256) void bias_k(const float* __restrict__ bq, const float* __restrict__ bk,
                                              const float* __restrict__ bv, const float* __restrict__ eb1,
                                              float* __restrict__ qkvb, float* __restrict__ ebias) {
    int i = blockIdx.x * 256 + threadIdx.x;
    if (i < 6144) {
        int d = i / 1536, r = i - d * 1536; int sel = r >> 9, c = r & 511;
        const float* s = sel == 0 ? bq : (sel == 1 ? bk : bv);
        qkvb[i] = s[d * 512 + c];
    } else if (i < 6272) {
        int j = i - 6144;
        ebias[j] = j < 64 ? eb1[j] : 0.0f;
    }
}

// ---------------- LDS-staged double-buffered split-bf16 MFMA GEMM ----------------
// Tile 64(M)x64(N), BK=32, 256 threads = 4 waves (2x2 quadrants of 32x32).
// A is [M][lda] u16 hi/lo, W is [N][lda] u16 hi/lo (pre-transposed).
// LDS row layout: [row][128B] = hi k0..31 | lo k0..31, XOR-swizzled by ((row&7)<<4)
// applied on the *global source* side (global_load_lds writes linearly) and on
// the ds_read side (rule #21: both-sides-or-neither).
template <int KC, bool PARTIAL, bool GELU, bool RES, bool OUTF, bool OUTS>
__global__ __launch_bounds__(256) void gemm2(
    const u16* __restrict__ Ahi, const u16* __restrict__ Alo,
    const u16* __restrict__ Whi, const u16* __restrict__ Wlo,
    const float* __restrict__ bias, const float* __restrict__ Rres,
    float* __restrict__ C, u16* __restrict__ Chi, u16* __restrict__ Clo,
    float* __restrict__ part, int lda, int N) {
    __shared__ u16 sbuf[2][2][64][64];  // [buf][A/B][row][hi32|lo32]
    const int tid = threadIdx.x;
    const int l = tid & 63;
    const int w = tid >> 6;
    const int bn0 = blockIdx.x * 64;
    const int bm0 = blockIdx.y * 64;
    const int z = blockIdx.z;

    // staging source precompute: inst i covers LDS bytes [(i*4+w)*1024, +1024)
    const u16* gp[4];
#pragma unroll
    for (int i = 0; i < 4; ++i) {
        int o = (i * 4 + w) * 1024 + l * 16;
        int mat = o >> 13;               // 0 = A, 1 = B
        int r = (o >> 7) & 63;
        int slot = (o >> 4) & 7;         // physical 16B slot in row
        int lslot = slot ^ (r & 7);      // logical slot (inverse swizzle)
        int sel = lslot >> 2;            // 0 = hi, 1 = lo
        int kel = (lslot & 3) * 8;       // element offset within 32-k chunk
        const u16* basep;
        if (mat == 0) basep = (sel ? Alo : Ahi) + (size_t)(bm0 + r) * lda;
        else          basep = (sel ? Wlo : Whi) + (size_t)(bn0 + r) * lda;
        gp[i] = basep + kel + z * KC;
    }

    f32x4 acc[2][2] = {};
    constexpr int S = KC / 32;

    auto stage = [&](int buf, int ko) {
#pragma unroll
        for (int i = 0; i < 4; ++i) {
            __builtin_amdgcn_global_load_lds(
                (const __attribute__((address_space(1))) void*)(gp[i] + ko),
                (__attribute__((address_space(3))) void*)((char*)&sbuf[buf][0][0][0] + (i * 4 + w) * 1024),
                16, 0, 0);
        }
    };
    auto compute = [&](int buf) {
        bf16x8 a[2][2], b[2][2];
        int rA0 = (w & 1) * 32 + (l & 15);
        int rB0 = (w >> 1) * 32 + (l & 15);
        int lsl = l >> 4;
#pragma unroll
        for (int f = 0; f < 2; ++f) {
            int rA = rA0 + f * 16;
            int rB = rB0 + f * 16;
#pragma unroll
            for (int sel = 0; sel < 2; ++sel) {
                int psA = (lsl + sel * 4) ^ (rA & 7);
                int psB = (lsl + sel * 4) ^ (rB & 7);
                a[f][sel] = *(const bf16x8*)&sbuf[buf][0][rA][psA * 8];
                b[f][sel] = *(const bf16x8*)&sbuf[buf][1][rB][psB * 8];
            }
        }
#pragma unroll
        for (int fm = 0; fm < 2; ++fm)
#pragma unroll
            for (int fn = 0; fn < 2; ++fn) {
                acc[fm][fn] = __builtin_amdgcn_mfma_f32_16x16x32_bf16(a[fm][0], b[fn][0], acc[fm][fn], 0, 0, 0);
                acc[fm][fn] = __builtin_amdgcn_mfma_f32_16x16x32_bf16(a[fm][0], b[fn][1], acc[fm][fn], 0, 0, 0);
                acc[fm][fn] = __builtin_amdgcn_mfma_f32_16x16x32_bf16(a[fm][1], b[fn][0], acc[fm][fn], 0, 0, 0);
            }
    };

    stage(0, 0);
    __syncthreads();
#pragma unroll
    for (int s = 0; s < S; ++s) {
        if (s + 1 < S) stage((s + 1) & 1, (s + 1) * 32);
        compute(s & 1);
        __syncthreads();
    }

    int rb = bm0 + (w & 1) * 32 + (l >> 4) * 4;
    int cb = bn0 + (w >> 1) * 32 + (l & 15);
#pragma unroll
    for (int fm = 0; fm < 2; ++fm)
#pragma unroll
        for (int fn = 0; fn < 2; ++fn) {
            int col = cb + fn * 16;
            float bv = PARTIAL ? 0.f : bias[col];
#pragma unroll
            for (int r = 0; r < 4; ++r) {
                int row = rb + fm * 16 + r;
                float v = acc[fm][fn][r] + bv;
                if (PARTIAL) {
                    part[(size_t)z * 512 * N + (size_t)row * N + col] = v;
                } else {
                    if (GELU) v = gelu_f(v);
                    if (RES) v += Rres[(size_t)row * N + col];
                    if (OUTF) C[(size_t)row * N + col] = v;
                    if (OUTS) {
                        u16 h, lo2; bf_split(v, h, lo2);
                        Chi[(size_t)row * N + col] = h; Clo[(size_t)row * N + col] = lo2;
                    }
                }
            }
        }
}

// ---------------- split-K reduce + epilogue ----------------
template <int NZ, int NCOL, bool GELU, bool RES, bool OUTF, bool OUTS>
__global__ __launch_bounds__(256) void redk(const float* __restrict__ part,
                                            const float* __restrict__ bias,
                                            const float* __restrict__ R,
                                            float* __restrict__ C,
                                            u16* __restrict__ Chi, u16* __restrict__ Clo) {
    int idx = blockIdx.x * 256 + threadIdx.x;   // total = 512*NCOL
    int col = idx % NCOL;
    float v = bias[col];
#pragma unroll
    for (int zz = 0; zz < NZ; ++zz) v += part[(size_t)zz * 512 * NCOL + idx];
    if (GELU) v = gelu_f(v);
    if (RES) v += R[idx];
    if (OUTF) C[idx] = v;
    if (OUTS) { u16 h, l; bf_split(v, h, l); Chi[idx] = h; Clo[idx] = l; }
}

// ---------------- fused masked attention per (b, head, 16-row tile) ----------------
__global__ __launch_bounds__(256) void attn_k(const float* __restrict__ qkv,
                                              const float* __restrict__ tsym,
                                              u16* __restrict__ agghi, u16* __restrict__ agglo) {
    int tt = blockIdx.x, hh = blockIdx.y, b = blockIdx.z;
    __shared__ __align__(16) float Ks[128 * 68];
    __shared__ __align__(16) float Vt[64 * 132];
    __shared__ __align__(16) float Ss[16 * 132];
    int tid = threadIdx.x;
    {
        int j = tid >> 1, c0 = (tid & 1) * 32;
        const float* kr = qkv + ((size_t)(b * 128 + j)) * 1536 + 512 + hh * 64 + c0;
        const float* vr = kr + 512;
#pragma unroll
        for (int c = 0; c < 32; c += 4) {
            float4 kv = *(const float4*)(kr + c);
            float4 vv = *(const float4*)(vr + c);
            Ks[j * 68 + c0 + c + 0] = kv.x; Ks[j * 68 + c0 + c + 1] = kv.y;
            Ks[j * 68 + c0 + c + 2] = kv.z; Ks[j * 68 + c0 + c + 3] = kv.w;
            Vt[(c0 + c + 0) * 132 + j] = vv.x; Vt[(c0 + c + 1) * 132 + j] = vv.y;
            Vt[(c0 + c + 2) * 132 + j] = vv.z; Vt[(c0 + c + 3) * 132 + j] = vv.w;
        }
    }
    __syncthreads();
    {
        int j = tid & 127, th = tid >> 7;
        const float* qrow = qkv + ((size_t)(b * 128 + tt * 16 + th * 8)) * 1536 + hh * 64;
        float acc[8] = {0.f, 0.f, 0.f, 0.f, 0.f, 0.f, 0.f, 0.f};
        for (int d0 = 0; d0 < 64; d0 += 4) {
            float4 kv = *(const float4*)&Ks[j * 68 + d0];
#pragma unroll
            for (int r = 0; r < 8; ++r) {
                float4 qv = *(const float4*)(qrow + (size_t)r * 1536 + d0);
                acc[r] += qv.x * kv.x + qv.y * kv.y + qv.z * kv.z + qv.w * kv.w;
            }
        }
        const float* tsr = tsym + ((size_t)b << 14) + (size_t)(tt * 16 + th * 8) * 128 + j;
#pragma unroll
        for (int r = 0; r < 8; ++r) {
            int t = th * 8 + r;
            float sv = (tsr[r * 128] > 0.f) ? acc[r] * 0.125f : -INFINITY;
            Ss[t * 132 + j] = sv;
        }
    }
    __syncthreads();
    {
        int row = tid >> 4, l16 = tid & 15;
        float v[8]; float m = -INFINITY;
#pragma unroll
        for (int c = 0; c < 8; ++c) { v[c] = Ss[row * 132 + l16 + c * 16]; m = fmaxf(m, v[c]); }
#pragma unroll
        for (int off = 8; off; off >>= 1) m = fmaxf(m, __shfl_xor(m, off));
        float ssum = 0.f;
#pragma unroll
        for (int c = 0; c < 8; ++c) {
            float e = (v[c] == -INFINITY) ? 0.f : __expf(v[c] - m);
            v[c] = e; ssum += e;
        }
#pragma unroll
        for (int off = 8; off; off >>= 1) ssum += __shfl_xor(ssum, off);
        float inv = 1.0f / (ssum + 1e-12f);
#pragma unroll
        for (int c = 0; c < 8; ++c) Ss[row * 132 + l16 + c * 16] = v[c] * inv;
    }
    __syncthreads();
    {
        int d = tid & 63, tq = tid >> 6;
        float a0 = 0.f, a1 = 0.f, a2 = 0.f, a3 = 0.f;
        for (int j0 = 0; j0 < 128; j0 += 4) {
            float4 vv = *(const float4*)&Vt[d * 132 + j0];
            float4 s0 = *(const float4*)&Ss[(tq * 4 + 0) * 132 + j0];
            float4 s1 = *(const float4*)&Ss[(tq * 4 + 1) * 132 + j0];
            float4 s2 = *(const float4*)&Ss[(tq * 4 + 2) * 132 + j0];
            float4 s3 = *(const float4*)&Ss[(tq * 4 + 3) * 132 + j0];
            a0 += s0.x * vv.x + s0.y * vv.y + s0.z * vv.z + s0.w * vv.w;
            a1 += s1.x * vv.x + s1.y * vv.y + s1.z * vv.z + s1.w * vv.w;
            a2 += s2.x * vv.x + s2.y * vv.y + s2.z * vv.z + s2.w * vv.w;
            a3 += s3.x * vv.x + s3.y * vv.y + s3.z * vv.z + s3.w * vv.w;
        }
        float accv[4] = {a0, a1, a2, a3};
        int growbase = b * 128 + tt * 16;
#pragma unroll
        for (int i = 0; i < 4; ++i) {
            int t = tq * 4 + i;
            u16 h, l; bf_split(accv[i], h, l);
            size_t o = (size_t)(growbase + t) * 512 + hh * 64 + d;
            agghi[o] = h; agglo[o] = l;
        }
    }
}

// ---------------- fused per-edge MLP ----------------
__global__ __launch_bounds__(256) void edgemlp_k(const int* __restrict__ ei, int E,
                                                 const float* __restrict__ x,
                                                 const float* __restrict__ aebe,
                                                 const u16* __restrict__ ect_h, const u16* __restrict__ ect_l,
                                                 const float* __restrict__ ew2, const float* __restrict__ eb2,
                                                 const float* __restrict__ ew3, const float* __restrict__ eb3,
                                                 float* __restrict__ P) {
    __shared__ __align__(16) u16 Ph[32][40];
    __shared__ __align__(16) u16 Pl[32][40];
    __shared__ float G1[32][66];
    __shared__ float G2[32][66];
    __shared__ int s_src[32], s_dst[32];
    int tid = threadIdx.x;
    int e0 = blockIdx.x * 32;
    if (tid < 32) {
        int e = e0 + tid;
        s_src[tid] = e < E ? ei[e] : 0;
        s_dst[tid] = e < E ? ei[E + e] : 0;
    }
    __syncthreads();
    int lane = tid & 63, w = tid >> 6;
    int el = tid >> 3, kq = (tid & 7) * 4;
    const float* xi = x + (size_t)s_src[el] * 512;
    const float* xj = x + (size_t)s_dst[el] * 512;
    int l15 = lane & 15;
    int kf = (lane >> 4) * 8;
    int mf = (w & 1) * 16;
    int nf = (w >> 1) * 32;
    const u16* pB1h = ect_h + (size_t)(nf + l15) * 512 + kf;
    const u16* pB1l = ect_l + (size_t)(nf + l15) * 512 + kf;
    const u16* pB2h = ect_h + (size_t)(nf + 16 + l15) * 512 + kf;
    const u16* pB2l = ect_l + (size_t)(nf + 16 + l15) * 512 + kf;
    f32x4 acc0 = {0.f, 0.f, 0.f, 0.f}, acc1 = {0.f, 0.f, 0.f, 0.f};
    for (int k0 = 0; k0 < 512; k0 += 32) {
        float4 a = *(const float4*)(xi + k0 + kq);
        float4 bb = *(const float4*)(xj + k0 + kq);
        u16 h0, l0, h1, l1, h2, l2, h3, l3;
        bf_split(a.x * bb.x, h0, l0); bf_split(a.y * bb.y, h1, l1);
        bf_split(a.z * bb.z, h2, l2); bf_split(a.w * bb.w, h3, l3);
        __syncthreads();
        *(ushort4*)&Ph[el][kq] = make_ushort4(h0, h1, h2, h3);
        *(ushort4*)&Pl[el][kq] = make_ushort4(l0, l1, l2, l3);
        __syncthreads();
        bf16x8 ah = *(const bf16x8*)&Ph[mf + l15][kf];
        bf16x8 al = *(const bf16x8*)&Pl[mf + l15][kf];
        bf16x8 b1h = *(const bf16x8*)(pB1h + k0);
        bf16x8 b1l = *(const bf16x8*)(pB1l + k0);
        bf16x8 b2h = *(const bf16x8*)(pB2h + k0);
        bf16x8 b2l = *(const bf16x8*)(pB2l + k0);
        acc0 = __builtin_amdgcn_mfma_f32_16x16x32_bf16(ah, b1h, acc0, 0, 0, 0);
        acc1 = __builtin_amdgcn_mfma_f32_16x16x32_bf16(ah, b2h, acc1, 0, 0, 0);
        acc0 = __builtin_amdgcn_mfma_f32_16x16x32_bf16(ah, b1l, acc0, 0, 0, 0);
        acc1 = __builtin_amdgcn_mfma_f32_16x16x32_bf16(ah, b2l, acc1, 0, 0, 0);
        acc0 = __builtin_amdgcn_mfma_f32_16x16x32_bf16(al, b1h, acc0, 0, 0, 0);
        acc1 = __builtin_amdgcn_mfma_f32_16x16x32_bf16(al, b2h, acc1, 0, 0, 0);
    }
    int rb = mf + (lane >> 4) * 4;
#pragma unroll
    for (int f = 0; f < 2; ++f) {
        f32x4 a = f ? acc1 : acc0;
        int col = nf + f * 16 + l15;
#pragma unroll
        for (int r = 0; r < 4; ++r) {
            int e = rb + r;
            float c = a[r] + aebe[(size_t)s_src[e] * 128 + col] + aebe[(size_t)s_dst[e] * 128 + 64 + col];
            G1[e][col] = gelu_f(c);
        }
    }
    __syncthreads();
    {
        int col = tid & 63, eq = tid >> 6;
        float acc[8];
#pragma unroll
        for (int i = 0; i < 8; ++i) acc[i] = eb2[col];
        for (int m = 0; m < 64; ++m) {
            float wv = ew2[m * 64 + col];
#pragma unroll
            for (int i = 0; i < 8; ++i) acc[i] += G1[eq * 8 + i][m] * wv;
        }
#pragma unroll
        for (int i = 0; i < 8; ++i) G2[eq * 8 + i][col] = gelu_f(acc[i]);
    }
    __syncthreads();
    {
        int el2 = tid >> 3, c8 = (tid & 7) * 8;
        float p = 0.f;
#pragma unroll
        for (int i = 0; i < 8; ++i) p += G2[el2][c8 + i] * ew3[c8 + i];
        p += __shfl_xor(p, 1); p += __shfl_xor(p, 2); p += __shfl_xor(p, 4);
        if ((tid & 7) == 0 && e0 + el2 < E) {
            float logit = p + eb3[0];
            int s = s_src[el2], d2 = s_dst[el2];
            int bB = s >> 7, i2 = s & 127, j2 = d2 & 127;
            P[(bB << 14) + (i2 << 7) + j2] = 1.0f / (1.0f + expf(-logit));
        }
    }
}

// ---------------- final symmetrize + mask ----------------
__global__ __launch_bounds__(256) void final_k(const float* __restrict__ tsym,
                                               const float* __restrict__ P,
                                               float* __restrict__ out) {
    int idx = blockIdx.x * 256 + threadIdx.x;
    int b = idx >> 14, i = (idx >> 7) & 127, j = idx & 127;
    float o = 0.0f;
    if (i != j && tsym[idx] > 0.0f)
        o = 0.5f * (P[idx] + P[(b << 14) + (j << 7) + i]);
    out[idx] = o;
}

extern "C" void kernel_launch(void* const* d_in, const int* in_sizes, int n_in,
                              void* d_out, int out_size, void* d_ws, size_t ws_size,
                              hipStream_t stream) {
    const float* topo   = (const float*)d_in[0];
    const float* weight = (const float*)d_in[1];
    const int*   ei     = (const int*)d_in[2];
    const float* w_topo = (const float*)d_in[3];
    const float* b_topo = (const float*)d_in[4];
    const float* w_w    = (const float*)d_in[5];
    const float* b_w    = (const float*)d_in[6];
    const float* n_emb  = (const float*)d_in[7];
    const float* wq = (const float*)d_in[8];  const float* bq = (const float*)d_in[9];
    const float* wk = (const float*)d_in[10]; const float* bk = (const float*)d_in[11];
    const float* wv = (const float*)d_in[12]; const float* bv = (const float*)d_in[13];
    const float* wo = (const float*)d_in[14]; const float* bo = (const float*)d_in[15];
    const float* w1 = (const float*)d_in[16]; const float* b1 = (const float*)d_in[17];
    const float* w2 = (const float*)d_in[18]; const float* b2 = (const float*)d_in[19];
    const float* ew1 = (const float*)d_in[20]; const float* eb1 = (const float*)d_in[21];
    const float* ew2 = (const float*)d_in[22]; const float* eb2 = (const float*)d_in[23];
    const float* ew3 = (const float*)d_in[24]; const float* eb3 = (const float*)d_in[25];
    const int E = in_sizes[2] / 2;

    char* base = (char*)d_ws;
    size_t off = 0;
    auto alloc = [&](size_t bytes) { char* p = base + off; off += (bytes + 255) & ~(size_t)255; return p; };
    u16* qkvt_h = (u16*)alloc(3145728 * 2); u16* qkvt_l = (u16*)alloc(3145728 * 2);
    u16* wot_h  = (u16*)alloc(1048576 * 2); u16* wot_l  = (u16*)alloc(1048576 * 2);
    u16* w1t_h  = (u16*)alloc(4194304 * 2); u16* w1t_l  = (u16*)alloc(4194304 * 2);
    u16* w2t_h  = (u16*)alloc(4194304 * 2); u16* w2t_l  = (u16*)alloc(4194304 * 2);
    u16* eabt_h = (u16*)alloc(65536 * 2);   u16* eabt_l = (u16*)alloc(65536 * 2);
    u16* ect_h  = (u16*)alloc(32768 * 2);   u16* ect_l  = (u16*)alloc(32768 * 2);
    u16* h_hi   = (u16*)alloc(262144 * 2);  u16* h_lo   = (u16*)alloc(262144 * 2);
    u16* agg_hi = (u16*)alloc(262144 * 2);  u16* agg_lo = (u16*)alloc(262144 * 2);
    u16* mid_hi = (u16*)alloc(1048576 * 2); u16* mid_lo = (u16*)alloc(1048576 * 2);
    u16* x_hi   = (u16*)alloc(262144 * 2);  u16* x_lo   = (u16*)alloc(262144 * 2);
    float* qkvb  = (float*)alloc(6144 * 4);
    float* ebias = (float*)alloc(128 * 4);
    float* tsym  = (float*)alloc(65536 * 4);
    float* x     = (float*)alloc(262144 * 4);
    float* qkvo  = (float*)alloc(786432 * 4);
    float* aebe  = (float*)alloc(65536 * 4);
    float* P     = (float*)alloc(65536 * 4);
    float* pw    = (float*)alloc(1572864 * 4);   // split-K partials (max: qkv 2x512x1536)

    prep_k<<<3096, 256, 0, stream>>>(wq, wk, wv, wo, w1, w2, ew1,
                                     qkvt_h, qkvt_l, wot_h, wot_l, w1t_h, w1t_l,
                                     w2t_h, w2t_l, eabt_h, eabt_l, ect_h, ect_l);
    bias_k<<<25, 256, 0, stream>>>(bq, bk, bv, eb1, qkvb, ebias);
    tsym_k<<<256, 256, 0, stream>>>(topo, tsym);
    x0_k<<<1024, 256, 0, stream>>>(tsym, w_topo, b_topo, weight, w_w, b_w, n_emb, x);

    for (int d = 0; d < 4; ++d) {
        ln_k<<<512, 256, 0, stream>>>(x, h_hi, h_lo);
        // QKV: split-K x2 -> partials -> reduce(+bias)
        gemm2<256, true, false, false, false, false><<<dim3(24, 8, 2), 256, 0, stream>>>(
            h_hi, h_lo, qkvt_h + (size_t)d * 1536 * 512, qkvt_l + (size_t)d * 1536 * 512,
            nullptr, nullptr, nullptr, nullptr, nullptr, pw, 512, 1536);
        redk<2, 1536, false, false, true, false><<<3072, 256, 0, stream>>>(
            pw, qkvb + d * 1536, nullptr, qkvo, nullptr, nullptr);
        attn_k<<<dim3(8, 8, 4), 256, 0, stream>>>(qkvo, tsym, agg_hi, agg_lo);
        // WO: split-K x4
        gemm2<128, true, false, false, false, false><<<dim3(8, 8, 4), 256, 0, stream>>>(
            agg_hi, agg_lo, wot_h + (size_t)d * 512 * 512, wot_l + (size_t)d * 512 * 512,
            nullptr, nullptr, nullptr, nullptr, nullptr, pw, 512, 512);
        redk<4, 512, false, true, true, false><<<1024, 256, 0, stream>>>(
            pw, bo + d * 512, x, x, nullptr, nullptr);
        ln_k<<<512, 256, 0, stream>>>(x, h_hi, h_lo);
        // MLP1: full-K (256 blocks), gelu + split out
        gemm2<512, false, true, false, false, true><<<dim3(32, 8, 1), 256, 0, stream>>>(
            h_hi, h_lo, w1t_h + (size_t)d * 2048 * 512, w1t_l + (size_t)d * 2048 * 512,
            b1 + d * 2048, nullptr, nullptr, mid_hi, mid_lo, nullptr, 512, 2048);
        // MLP2: split-K x4
        gemm2<512, true, false, false, false, false><<<dim3(8, 8, 4), 256, 0, stream>>>(
            mid_hi, mid_lo, w2t_h + (size_t)d * 512 * 2048, w2t_l + (size_t)d * 512 * 2048,
            nullptr, nullptr, nullptr, nullptr, nullptr, pw, 2048, 512);
        if (d < 3) {
            redk<4, 512, false, true, true, false><<<1024, 256, 0, stream>>>(
                pw, b2 + d * 512, x, x, nullptr, nullptr);
        } else {
            redk<4, 512, false, true, true, true><<<1024, 256, 0, stream>>>(
                pw, b2 + d * 512, x, x, x_hi, x_lo);
        }
    }

    // edge-final MLP: per-node ae/be terms (split-K), then fused per-edge kernel
    gemm2<128, true, false, false, false, false><<<dim3(2, 8, 4), 256, 0, stream>>>(
        x_hi, x_lo, eabt_h, eabt_l, nullptr, nullptr, nullptr, nullptr, nullptr, pw, 512, 128);
    redk<4, 128, false, false, true, false><<<256, 256, 0, stream>>>(
        pw, ebias, nullptr, aebe, nullptr, nullptr);
    edgemlp_k<<<(E + 31) / 32, 256, 0, stream>>>(ei, E, x, aebe, ect_h, ect_l,
                                                 ew2, eb2, ew3, eb3, P);
    final_k<<<256, 256, 0, stream>>>(tsym, P, (float*)d_out);
}